// Round 10
// baseline (239.290 us; speedup 1.0000x reference)
//
#include <hip/hip_runtime.h>
#include <hip/hip_bf16.h>

// Fused attention block: QKV proj -> causal MHA -> dense proj.
// SEQ=2048, BATCH=2, HIDDEN=2048, HEADS=16, HEAD_DIM=128.
// R10: GEMMs moved to mfma_f32_32x32x16_bf16 (µbench ceiling 2382 vs 2075
// for 16x16x32; half the instruction count) with a uniform 4-phase schedule:
// phase = (m-tile x kstep-pair), 6 MFMA/phase (QKV), B-frags register-reused
// across m-halves. Early staging (kt+1 fully at ph0, A-m0(kt+2) at ph3),
// one vmcnt(1)/tile. Exact-fill grids kept. attn/cvt/vtrans frozen (R9).

typedef __bf16 bf16x8 __attribute__((ext_vector_type(8)));
typedef __bf16 bf16x4 __attribute__((ext_vector_type(4)));
typedef float  f32x4  __attribute__((ext_vector_type(4)));
typedef float  f32x16 __attribute__((ext_vector_type(16)));

#define MROWS 4096   // SEQ*BATCH
#define NQKV  6144   // 3*HIDDEN

__device__ __forceinline__ void g2l16(const void* g, void* l) {
  __builtin_amdgcn_global_load_lds(
      (const __attribute__((address_space(1))) unsigned int*)g,
      (__attribute__((address_space(3))) unsigned int*)l, 16, 0, 0);
}

// ---------------- fp32 -> bf16 convert (all three tensors, one launch) ------
__global__ void cvt3_kernel(const float* __restrict__ x, const float* __restrict__ wq,
                            const float* __restrict__ wd, __bf16* __restrict__ xb,
                            __bf16* __restrict__ wqb, __bf16* __restrict__ wdb) {
  const int N1 = 2097152, N2 = 3145728;   // float4 counts: x, wqkv (wd = rest)
  int i = blockIdx.x * 256 + threadIdx.x;
  const float4* src; bf16x4* dst; int j;
  if (i < N1)           { src = (const float4*)x;  dst = (bf16x4*)xb;  j = i; }
  else if (i < N1 + N2) { src = (const float4*)wq; dst = (bf16x4*)wqb; j = i - N1; }
  else                  { src = (const float4*)wd; dst = (bf16x4*)wdb; j = i - N1 - N2; }
  float4 v = src[j];
  bf16x4 o = { (__bf16)v.x, (__bf16)v.y, (__bf16)v.z, (__bf16)v.w };
  dst[j] = o;
}

// ---------------- 32x32 GEMM: C[M][N] = A[M][K] * B[N][K]^T + bias ----------
// BM=128, BN=128*NT, BK=64. 8 waves (2M x 4N); per-wave 64 x 32*NT =
// 2 x NT tiles of 32x32. Phases (uniform, 2*NT MFMA each):
//   ph0: read A(m0,ks01)+B(all,ks01); stage A-m1(kt+1)+B(kt+1)->nbuf; MFMA m0
//   ph1: read A(m1,ks01);                                            MFMA m1
//   ph2: read A(m0,ks23)+B(all,ks23);                                MFMA m0
//   ph3: read A(m1,ks23); stage A-m0(kt+2)->buf; MFMA m1; vmcnt(1)
// B-frags register-reused across both m-phases of a ks-pair. Every stage
// lands >=1 barrier after its region's last LDS read (derived per-region).
// vmcnt(1) drains tile kt+1 exactly (A-m0(kt+2), issued ph3, stays in flight).
// A/B frag: row/col=lane&31, k=(lane>>5)*8+e.  C/D: col=lane&31,
// row=(reg&3)+8*(reg>>2)+4*(lane>>5)  [m74/m101-verified].
// LDS swizzle chunk^=(row&7) via pre-swizzled global source (rule #21).
#define SBAR asm volatile("s_barrier" ::: "memory")
#define LGKM0 asm volatile("s_waitcnt lgkmcnt(0)" ::: "memory")
#define LDA32(BUFP, MTI, KP)                                                    \
  { int row = wm*64 + (MTI)*32 + l31;                                           \
    _Pragma("unroll")                                                           \
    for (int j = 0; j < 2; ++j) {                                               \
      int ch = ((KP)*2 + j)*2 + hi;                                             \
      af[j] = *(const bf16x8*)((BUFP) + row*128 + ((ch ^ (row & 7)) << 4));     \
    } }
#define LDB32(BUFP, KP)                                                         \
  { _Pragma("unroll")                                                           \
    for (int n2 = 0; n2 < NT; ++n2) {                                           \
      int row = wn*(32*NT) + n2*32 + l31;                                       \
      _Pragma("unroll")                                                         \
      for (int j = 0; j < 2; ++j) {                                             \
        int ch = ((KP)*2 + j)*2 + hi;                                           \
        bfv[n2][j] = *(const bf16x8*)((BUFP) + ABYTES + row*128 + ((ch ^ (row & 7)) << 4)); \
      } } }
#define MM32(MTI)                                                               \
  { _Pragma("unroll")                                                           \
    for (int n2 = 0; n2 < NT; ++n2) {                                           \
      acc[MTI][n2] = __builtin_amdgcn_mfma_f32_32x32x16_bf16(af[0], bfv[n2][0], acc[MTI][n2], 0,0,0); \
      acc[MTI][n2] = __builtin_amdgcn_mfma_f32_32x32x16_bf16(af[1], bfv[n2][1], acc[MTI][n2], 0,0,0); \
    } }

template<int NT, int C_BF16>
__global__ __launch_bounds__(512, 1)
void gemm32(const __bf16* __restrict__ A, const __bf16* __restrict__ B,
            const float* __restrict__ bias, void* __restrict__ Cout,
            int M, int N, int K) {
  constexpr int BM = 128, BN = 128*NT;
  constexpr int ABYTES = BM*128;
  constexpr int I_B = BN/64;        // B g2l16 per thread

  const int tid = threadIdx.x, lane = tid & 63, w = tid >> 6;
  const int wm = w >> 2, wn = w & 3;
  const int m0 = blockIdx.y*BM, n0 = blockIdx.x*BN;
  const int l31 = lane & 31, hi = lane >> 5;
  const int l8 = lane >> 3;
  const int swch = (lane & 7) ^ l8;           // pre-swizzled global chunk

  __shared__ char smem[2][ABYTES + BN*128];

  f32x16 acc[2][NT] = {};

  const int nt = K >> 6;

  // stage A-region r (rows {h*64 + r*32 + [0,32) : h in 0,1} = 8 1KB units)
  auto stA = [&](int kt2, int r, char* dst) {
    int rb = (w >> 2)*64 + r*32 + (w & 3)*8;
    g2l16(A + (size_t)(m0 + rb + l8)*K + kt2*64 + swch*8, dst + rb*128);
  };
  auto stB = [&](int kt2, char* dst) {
    #pragma unroll
    for (int q = 0; q < I_B; ++q) {
      int rb = (q*8 + w)*8;
      g2l16(B + (size_t)(n0 + rb + l8)*K + kt2*64 + swch*8, dst + ABYTES + rb*128);
    }
  };

  auto tile = [&](int kt, char* buf, char* nbuf) {
    bf16x8 af[2], bfv[NT][2];
    // ph0: A(m0,ks01)+B(ks01); stage A-m1(kt+1), B(kt+1) -> nbuf
    LDA32(buf, 0, 0)
    LDB32(buf, 0)
    stA(kt+1, 1, nbuf); stB(kt+1, nbuf);
    SBAR; LGKM0;
    __builtin_amdgcn_s_setprio(1); MM32(0) __builtin_amdgcn_s_setprio(0);
    SBAR;
    // ph1: A(m1,ks01); B held in regs
    LDA32(buf, 1, 0)
    SBAR; LGKM0;
    __builtin_amdgcn_s_setprio(1); MM32(1) __builtin_amdgcn_s_setprio(0);
    SBAR;
    // ph2: A(m0,ks23)+B(ks23)
    LDA32(buf, 0, 1)
    LDB32(buf, 1)
    SBAR; LGKM0;
    __builtin_amdgcn_s_setprio(1); MM32(0) __builtin_amdgcn_s_setprio(0);
    SBAR;
    // ph3: A(m1,ks23); stage A-m0(kt+2)->buf (its reads done at ph2);
    // counted drain: tile kt+1 fully landed, A-m0(kt+2) stays in flight.
    LDA32(buf, 1, 1)
    stA(kt+2, 0, buf);
    SBAR; LGKM0;
    __builtin_amdgcn_s_setprio(1); MM32(1) __builtin_amdgcn_s_setprio(0);
    asm volatile("s_waitcnt vmcnt(1)" ::: "memory");
    SBAR;
  };

  // prologue: tile0 complete + A-m0(1); drain to vmcnt(1)
  stA(0, 0, smem[0]); stA(0, 1, smem[0]); stB(0, smem[0]);
  stA(1, 0, smem[1]);
  asm volatile("s_waitcnt vmcnt(1)" ::: "memory");
  SBAR;

  for (int kt = 0; kt < nt; kt += 2) {
    tile(kt,     smem[0], smem[1]);
    tile(kt + 1, smem[1], smem[0]);
  }
  // phantom stages (kt2 <= nt+1) read <=128 elems past panel ends into
  // adjacent mapped ws buffers; their LDS regions are never read again.

  // epilogue: C/D col=lane&31, row=(reg&3)+8*(reg>>2)+4*hi (m74/m101)
  const int orow0 = m0 + wm*64;
  const int ocol0 = n0 + wn*(32*NT);
  #pragma unroll
  for (int mt = 0; mt < 2; ++mt) {
    #pragma unroll
    for (int n2 = 0; n2 < NT; ++n2) {
      int col = ocol0 + n2*32 + l31;
      float bv = bias[col];
      #pragma unroll
      for (int rg = 0; rg < 16; ++rg) {
        int row = orow0 + mt*32 + (rg & 3) + 8*(rg >> 2) + 4*hi;
        float v = acc[mt][n2][rg] + bv;
        size_t idx = (size_t)row * N + col;
        if (C_BF16) ((__bf16*)Cout)[idx] = (__bf16)v;
        else        ((float*)Cout)[idx]  = v;
      }
    }
  }
}

// ---------------- V transpose: mixed V-slice -> vbuf[bn][d][t] ----------------
__global__ __launch_bounds__(256, 2)
void vtrans(const __bf16* __restrict__ mixed, __bf16* __restrict__ vbuf) {
  const int tid = threadIdx.x;
  const int bn = blockIdx.x;          // b*16 + n
  const int b = bn >> 4, n = bn & 15;
  const int t0 = blockIdx.y * 128;
  __shared__ __bf16 tile[128][128];   // swizzled: chunk ^= (row>>3)&7

  #pragma unroll
  for (int q = 0; q < 8; ++q) {
    int lin = q * 256 + tid;
    int r = lin >> 4, ch = lin & 15;
    bf16x8 v = *(const bf16x8*)(mixed + (size_t)(t0 + r) * 12288 + (size_t)b * 6144 + n * 384 + 256 + ch * 8);
    int sch = ch ^ ((r >> 3) & 7);
    *(bf16x8*)((char*)tile + r * 256 + sch * 16) = v;
  }
  __syncthreads();
  #pragma unroll
  for (int q = 0; q < 8; ++q) {
    int lin = q * 256 + tid;
    int d = lin >> 4, tc = (lin & 15) * 8;
    bf16x8 v;
    #pragma unroll
    for (int j = 0; j < 8; ++j) {
      int row = tc + j;
      int swb = (d * 2) ^ (((row >> 3) & 7) << 4);
      v[j] = *(const __bf16*)((const char*)tile + row * 256 + swb);
    }
    *(bf16x8*)(vbuf + ((size_t)bn * 128 + d) * 2048 + t0 + tc) = v;
  }
}

// ---------------- flash attention (R7/R9 verified version) ----------------
// grid (8 pairs, 32 bn); 512 threads = 8 waves x 16 q-rows. Mirror-pair qt
// loop: exactly 34 KV iters/block; LDS 84KB pins 1 block/CU.
// Fixed-reference softmax P = exp(S*sc - 8); l reduced once per q-tile.
struct SmemA {
  __bf16 k[2][64][128];   // 32KB  (aliased by Q staging area)
  __bf16 v[2][128][64];   // 32KB
  __bf16 p[8][16][64];    // 16KB per-wave private P
};
union SmemUA { __bf16 q[128][128]; SmemA s; char pad[86016]; };

__global__ __launch_bounds__(512, 1)
void attn_kernel(const __bf16* __restrict__ mixed, const __bf16* __restrict__ vbuf,
                 __bf16* __restrict__ ctx) {
  const int tid = threadIdx.x, lane = tid & 63, w = tid >> 6;   // w in 0..7
  const int bn = blockIdx.y;
  const int b = bn >> 4, n = bn & 15;
  const int fr = lane & 15, g = lane >> 4;

  __shared__ SmemUA sm;
  const __bf16* vb = vbuf + (size_t)bn * 128 * 2048;
  const __bf16* mixb = mixed + (size_t)b * 6144 + n * 384;
  char* pbase = (char*)sm.s.p + w * 2048;

  auto stage_kv = [&](int k0, int buf) {
    #pragma unroll
    for (int qq = 0; qq < 2; ++qq) {
      int t = qq * 512 + tid;
      int r = t >> 4, ch = (t & 15) ^ (r & 7);
      g2l16(mixb + (size_t)(k0 + r) * 12288 + 128 + ch * 8,
            (char*)sm.s.k[buf] + qq * 8192 + w * 1024);
    }
    #pragma unroll
    for (int qq = 0; qq < 2; ++qq) {
      int t = qq * 512 + tid;
      int d = t >> 3, i = (t & 7) ^ (d & 7);
      g2l16(vb + (size_t)d * 2048 + k0 + i * 8,
            (char*)sm.s.v[buf] + qq * 8192 + w * 1024);
    }
  };

  #pragma unroll 1
  for (int phase = 0; phase < 2; ++phase) {
    const int qt = phase ? (int)blockIdx.x : (15 - (int)blockIdx.x);  // heavy first
    const int qs = qt * 128;

    __syncthreads();   // prior phase fully done before Q restage (aliases K dbuf)

    // ---- stage Q [128][128] (pre-swizzled source) ----
    #pragma unroll
    for (int qq = 0; qq < 4; ++qq) {
      int t = qq * 512 + tid;
      int r = t >> 4, ch = (t & 15) ^ (r & 7);
      g2l16(mixb + (size_t)(qs + r) * 12288 + ch * 8,
            (char*)sm.q + qq * 8192 + w * 1024);
    }
    asm volatile("s_waitcnt vmcnt(0)" ::: "memory");
    __syncthreads();

    bf16x8 qf[4];
    {
      const int row = w * 16 + fr;
      #pragma unroll
      for (int ks = 0; ks < 4; ++ks) {
        int ch = (ks * 4 + g) ^ (row & 7);
        qf[ks] = *(const bf16x8*)((const char*)sm.q + row * 256 + ch * 16);
      }
    }
    asm volatile("s_waitcnt lgkmcnt(0)" ::: "memory");
    __syncthreads();   // all qf reads landed before K staging overwrites Q area

    f32x4 O[8] = {};
    float lsum[4] = {0.f, 0.f, 0.f, 0.f};

    const int nt = (qs + 128) >> 6;
    int cur = 0;
    stage_kv(0, 0);

    #pragma unroll 1
    for (int it = 0; it < nt; ++it) {
      const int k0 = it * 64;
      asm volatile("s_waitcnt vmcnt(0)" ::: "memory");   // buf[cur] landed
      __syncthreads();                                    // ...for ALL waves
      if (it + 1 < nt) stage_kv((it + 1) * 64, cur ^ 1);  // fly under compute

      // ---- QK^T: S[16 q][64 kv] per wave ----
      f32x4 S[4] = {};
      __builtin_amdgcn_s_setprio(1);
      #pragma unroll
      for (int ks = 0; ks < 4; ++ks) {
        bf16x8 kf[4];
        #pragma unroll
        for (int fn = 0; fn < 4; ++fn) {
          int row = fn * 16 + fr;
          int ch = (ks * 4 + g) ^ (row & 7);
          kf[fn] = *(const bf16x8*)((const char*)sm.s.k[cur] + row * 256 + ch * 16);
        }
        #pragma unroll
        for (int fn = 0; fn < 4; ++fn)
          S[fn] = __builtin_amdgcn_mfma_f32_16x16x32_bf16(qf[ks], kf[fn], S[fn], 0, 0, 0);
      }
      __builtin_amdgcn_s_setprio(0);

      // ---- fixed-reference softmax: P = exp(S*sc - 8), masked -> 0 ----
      const float sc = 0.08838834764831845f;   // 1/sqrt(128)
      const bool needmask = (k0 + 63 > qs + w * 16);
      #pragma unroll
      for (int fn = 0; fn < 4; ++fn)
        #pragma unroll
        for (int r = 0; r < 4; ++r) {
          float p = __expf(fmaf(S[fn][r], sc, -8.0f));
          if (needmask) {
            int qrow = qs + w * 16 + g * 4 + r;
            int kcol = k0 + fn * 16 + fr;
            if (kcol > qrow) p = 0.f;
          }
          S[fn][r] = p;
          lsum[r] += p;
        }

      // ---- P -> LDS (per-wave private, swizzled) ----
      #pragma unroll
      for (int fn = 0; fn < 4; ++fn)
        #pragma unroll
        for (int r = 0; r < 4; ++r) {
          int prow = g * 4 + r;
          int colb = (fn * 16 + fr) * 2;
          *(__bf16*)(pbase + prow * 128 + (colb ^ ((prow & 7) << 4))) = (__bf16)S[fn][r];
        }

      // ---- PV: O += P * V (no rescale -- P reference is fixed) ----
      __builtin_amdgcn_s_setprio(1);
      #pragma unroll
      for (int ks2 = 0; ks2 < 2; ++ks2) {
        bf16x8 pa;
        {
          int ch = (ks2 * 4 + g) ^ (fr & 7);
          pa = *(const bf16x8*)(pbase + fr * 128 + ch * 16);
        }
        #pragma unroll
        for (int fn2 = 0; fn2 < 8; ++fn2) {
          int vrow = fn2 * 16 + fr;
          int ch = (ks2 * 4 + g) ^ (vrow & 7);
          bf16x8 vf = *(const bf16x8*)((const char*)sm.s.v[cur] + vrow * 128 + ch * 16);
          O[fn2] = __builtin_amdgcn_mfma_f32_16x16x32_bf16(pa, vf, O[fn2], 0, 0, 0);
        }
      }
      __builtin_amdgcn_s_setprio(0);
      cur ^= 1;
    }

    // ---- epilogue: one cross-lane l reduce per q-tile, then ctx write ----
    #pragma unroll
    for (int r = 0; r < 4; ++r) {
      float l = lsum[r];
      #pragma unroll
      for (int off = 1; off < 16; off <<= 1)
        l += __shfl_xor(l, off);
      float inv = 1.f / l;
      int qrow = qs + w * 16 + g * 4 + r;
      size_t rowb = ((size_t)qrow * 2 + b) * 2048 + n * 128;
      #pragma unroll
      for (int fn2 = 0; fn2 < 8; ++fn2)
        ctx[rowb + fn2 * 16 + fr] = (__bf16)(O[fn2][r] * inv);
    }
  }
}

extern "C" void kernel_launch(void* const* d_in, const int* in_sizes, int n_in,
                              void* d_out, int out_size, void* d_ws, size_t ws_size,
                              hipStream_t stream) {
  const float* x    = (const float*)d_in[0];
  // d_in[1] = mask: structurally causal, applied analytically in attn_kernel
  const float* wqkv = (const float*)d_in[2];
  const float* bqkv = (const float*)d_in[3];
  const float* wd   = (const float*)d_in[4];
  const float* bd   = (const float*)d_in[5];

  char* ws = (char*)d_ws;
  __bf16* xb    = (__bf16*)(ws);                 // 16.8MB (reused as ctx later)
  __bf16* wqkvb = (__bf16*)(ws + 16777216);      // 25.2MB
  __bf16* wdb   = (__bf16*)(ws + 41943040);      // 8.4MB
  __bf16* mixed = (__bf16*)(ws + 50331648);      // 50.3MB
  __bf16* vbuf  = (__bf16*)(ws + 100663296);     // 16.8MB  (total 117.4MB)
  __bf16* ctx   = xb;                            // xb dead after QKV GEMM

  cvt3_kernel<<<dim3(24576), 256, 0, stream>>>(x, wqkv, wd, xb, wqkvb, wdb);

  // QKV: BM=128 x BN=384 -> grid 16x32 = 512 blocks = 2 exact rounds @1/CU
  gemm32<3,1><<<dim3(16, 32), 512, 0, stream>>>(xb, wqkvb, bqkv, (void*)mixed, MROWS, NQKV, 2048);
  vtrans<<<dim3(32, 16), 256, 0, stream>>>(mixed, vbuf);
  attn_kernel<<<dim3(8, 32), 512, 0, stream>>>(mixed, vbuf, ctx);
  // dense: BM=128 x BN=256 -> grid 8x32 = 256 blocks = 1 exact round
  gemm32<2,0><<<dim3(8, 32), 512, 0, stream>>>(ctx, wdb, bd, d_out, MROWS, 2048, 2048);
}

// Round 11
// 234.370 us; speedup vs baseline: 1.0210x; 1.0210x over previous
//
#include <hip/hip_runtime.h>
#include <hip/hip_bf16.h>

// Fused attention block: QKV proj -> causal MHA -> dense proj.
// SEQ=2048, BATCH=2, HIDDEN=2048, HEADS=16, HEAD_DIM=128.
// R11: R10 + bank-conflict fix for the 32x32 frag reads. Bank = byte-in-row
// (128B row stride = bank period), and 32-row-span reads with only row&7 in
// the chunk XOR put lanes {l,l+8,l+16,l+24} on the same 4 banks (1e7
// conflicts, R10). Fix: chunk ^= (row>>3)&3 on reads; staging source
// swch ^= (w&3) (algebraically = (unit_row>>3)&3 for every stage unit) --
// same bijection on both sides (rule #21). Everything else = R10.

typedef __bf16 bf16x8 __attribute__((ext_vector_type(8)));
typedef __bf16 bf16x4 __attribute__((ext_vector_type(4)));
typedef float  f32x4  __attribute__((ext_vector_type(4)));
typedef float  f32x16 __attribute__((ext_vector_type(16)));

#define MROWS 4096   // SEQ*BATCH
#define NQKV  6144   // 3*HIDDEN

__device__ __forceinline__ void g2l16(const void* g, void* l) {
  __builtin_amdgcn_global_load_lds(
      (const __attribute__((address_space(1))) unsigned int*)g,
      (__attribute__((address_space(3))) unsigned int*)l, 16, 0, 0);
}

// ---------------- fp32 -> bf16 convert (all three tensors, one launch) ------
__global__ void cvt3_kernel(const float* __restrict__ x, const float* __restrict__ wq,
                            const float* __restrict__ wd, __bf16* __restrict__ xb,
                            __bf16* __restrict__ wqb, __bf16* __restrict__ wdb) {
  const int N1 = 2097152, N2 = 3145728;   // float4 counts: x, wqkv (wd = rest)
  int i = blockIdx.x * 256 + threadIdx.x;
  const float4* src; bf16x4* dst; int j;
  if (i < N1)           { src = (const float4*)x;  dst = (bf16x4*)xb;  j = i; }
  else if (i < N1 + N2) { src = (const float4*)wq; dst = (bf16x4*)wqb; j = i - N1; }
  else                  { src = (const float4*)wd; dst = (bf16x4*)wdb; j = i - N1 - N2; }
  float4 v = src[j];
  bf16x4 o = { (__bf16)v.x, (__bf16)v.y, (__bf16)v.z, (__bf16)v.w };
  dst[j] = o;
}

// ---------------- 32x32 GEMM: C[M][N] = A[M][K] * B[N][K]^T + bias ----------
// BM=128, BN=128*NT, BK=64. 8 waves (2M x 4N); per-wave 64 x 32*NT =
// 2 x NT tiles of 32x32. Phases (uniform, 2*NT MFMA each):
//   ph0: read A(m0,ks01)+B(all,ks01); stage A-m1(kt+1)+B(kt+1)->nbuf; MFMA m0
//   ph1: read A(m1,ks01);                                            MFMA m1
//   ph2: read A(m0,ks23)+B(all,ks23);                                MFMA m0
//   ph3: read A(m1,ks23); stage A-m0(kt+2)->buf; MFMA m1; vmcnt(1)
// B-frags register-reused across both m-phases of a ks-pair.
// A/B frag: row/col=lane&31, k=(lane>>5)*8+e.  C/D: col=lane&31,
// row=(reg&3)+8*(reg>>2)+4*(lane>>5)  [m74/m101-verified, R10 absmax-ok].
// LDS swizzle: chunk = ch ^ (row&7) ^ ((row>>3)&3), staged via pre-swizzled
// global source swch = (lane&7) ^ (lane>>3) ^ (w&3).
#define SBAR asm volatile("s_barrier" ::: "memory")
#define LGKM0 asm volatile("s_waitcnt lgkmcnt(0)" ::: "memory")
#define SWZ(CH, ROW) ((((CH) ^ ((ROW) & 7) ^ (((ROW) >> 3) & 3)) << 4))
#define LDA32(BUFP, MTI, KP)                                                    \
  { int row = wm*64 + (MTI)*32 + l31;                                           \
    _Pragma("unroll")                                                           \
    for (int j = 0; j < 2; ++j) {                                               \
      int ch = ((KP)*2 + j)*2 + hi;                                             \
      af[j] = *(const bf16x8*)((BUFP) + row*128 + SWZ(ch, row));                \
    } }
#define LDB32(BUFP, KP)                                                         \
  { _Pragma("unroll")                                                           \
    for (int n2 = 0; n2 < NT; ++n2) {                                           \
      int row = wn*(32*NT) + n2*32 + l31;                                       \
      _Pragma("unroll")                                                         \
      for (int j = 0; j < 2; ++j) {                                             \
        int ch = ((KP)*2 + j)*2 + hi;                                           \
        bfv[n2][j] = *(const bf16x8*)((BUFP) + ABYTES + row*128 + SWZ(ch, row)); \
      } } }
#define MM32(MTI)                                                               \
  { _Pragma("unroll")                                                           \
    for (int n2 = 0; n2 < NT; ++n2) {                                           \
      acc[MTI][n2] = __builtin_amdgcn_mfma_f32_32x32x16_bf16(af[0], bfv[n2][0], acc[MTI][n2], 0,0,0); \
      acc[MTI][n2] = __builtin_amdgcn_mfma_f32_32x32x16_bf16(af[1], bfv[n2][1], acc[MTI][n2], 0,0,0); \
    } }

template<int NT, int C_BF16>
__global__ __launch_bounds__(512, 1)
void gemm32(const __bf16* __restrict__ A, const __bf16* __restrict__ B,
            const float* __restrict__ bias, void* __restrict__ Cout,
            int M, int N, int K) {
  constexpr int BM = 128, BN = 128*NT;
  constexpr int ABYTES = BM*128;
  constexpr int I_B = BN/64;        // B g2l16 per thread

  const int tid = threadIdx.x, lane = tid & 63, w = tid >> 6;
  const int wm = w >> 2, wn = w & 3;
  const int m0 = blockIdx.y*BM, n0 = blockIdx.x*BN;
  const int l31 = lane & 31, hi = lane >> 5;
  const int l8 = lane >> 3;
  // pre-swizzled global chunk: every stage unit base rb has (rb>>3)&3 == w&3
  const int swch = (lane & 7) ^ l8 ^ (w & 3);

  __shared__ char smem[2][ABYTES + BN*128];

  f32x16 acc[2][NT] = {};

  const int nt = K >> 6;

  // stage A-region r (rows {h*64 + r*32 + [0,32) : h in 0,1} = 8 1KB units)
  auto stA = [&](int kt2, int r, char* dst) {
    int rb = (w >> 2)*64 + r*32 + (w & 3)*8;
    g2l16(A + (size_t)(m0 + rb + l8)*K + kt2*64 + swch*8, dst + rb*128);
  };
  auto stB = [&](int kt2, char* dst) {
    #pragma unroll
    for (int q = 0; q < I_B; ++q) {
      int rb = (q*8 + w)*8;
      g2l16(B + (size_t)(n0 + rb + l8)*K + kt2*64 + swch*8, dst + ABYTES + rb*128);
    }
  };

  auto tile = [&](int kt, char* buf, char* nbuf) {
    bf16x8 af[2], bfv[NT][2];
    // ph0: A(m0,ks01)+B(ks01); stage A-m1(kt+1), B(kt+1) -> nbuf
    LDA32(buf, 0, 0)
    LDB32(buf, 0)
    stA(kt+1, 1, nbuf); stB(kt+1, nbuf);
    SBAR; LGKM0;
    __builtin_amdgcn_s_setprio(1); MM32(0) __builtin_amdgcn_s_setprio(0);
    SBAR;
    // ph1: A(m1,ks01); B held in regs
    LDA32(buf, 1, 0)
    SBAR; LGKM0;
    __builtin_amdgcn_s_setprio(1); MM32(1) __builtin_amdgcn_s_setprio(0);
    SBAR;
    // ph2: A(m0,ks23)+B(ks23)
    LDA32(buf, 0, 1)
    LDB32(buf, 1)
    SBAR; LGKM0;
    __builtin_amdgcn_s_setprio(1); MM32(0) __builtin_amdgcn_s_setprio(0);
    SBAR;
    // ph3: A(m1,ks23); stage A-m0(kt+2)->buf (its reads done at ph2);
    // counted drain: tile kt+1 fully landed, A-m0(kt+2) stays in flight.
    LDA32(buf, 1, 1)
    stA(kt+2, 0, buf);
    SBAR; LGKM0;
    __builtin_amdgcn_s_setprio(1); MM32(1) __builtin_amdgcn_s_setprio(0);
    asm volatile("s_waitcnt vmcnt(1)" ::: "memory");
    SBAR;
  };

  // prologue: tile0 complete + A-m0(1); drain to vmcnt(1)
  stA(0, 0, smem[0]); stA(0, 1, smem[0]); stB(0, smem[0]);
  stA(1, 0, smem[1]);
  asm volatile("s_waitcnt vmcnt(1)" ::: "memory");
  SBAR;

  for (int kt = 0; kt < nt; kt += 2) {
    tile(kt,     smem[0], smem[1]);
    tile(kt + 1, smem[1], smem[0]);
  }
  // phantom stages (kt2 <= nt+1) read <=128 elems past panel ends into
  // adjacent mapped ws buffers; their LDS regions are never read again.

  // epilogue: C/D col=lane&31, row=(reg&3)+8*(reg>>2)+4*hi (m74/m101)
  const int orow0 = m0 + wm*64;
  const int ocol0 = n0 + wn*(32*NT);
  #pragma unroll
  for (int mt = 0; mt < 2; ++mt) {
    #pragma unroll
    for (int n2 = 0; n2 < NT; ++n2) {
      int col = ocol0 + n2*32 + l31;
      float bv = bias[col];
      #pragma unroll
      for (int rg = 0; rg < 16; ++rg) {
        int row = orow0 + mt*32 + (rg & 3) + 8*(rg >> 2) + 4*hi;
        float v = acc[mt][n2][rg] + bv;
        size_t idx = (size_t)row * N + col;
        if (C_BF16) ((__bf16*)Cout)[idx] = (__bf16)v;
        else        ((float*)Cout)[idx]  = v;
      }
    }
  }
}

// ---------------- V transpose: mixed V-slice -> vbuf[bn][d][t] ----------------
__global__ __launch_bounds__(256, 2)
void vtrans(const __bf16* __restrict__ mixed, __bf16* __restrict__ vbuf) {
  const int tid = threadIdx.x;
  const int bn = blockIdx.x;          // b*16 + n
  const int b = bn >> 4, n = bn & 15;
  const int t0 = blockIdx.y * 128;
  __shared__ __bf16 tile[128][128];   // swizzled: chunk ^= (row>>3)&7

  #pragma unroll
  for (int q = 0; q < 8; ++q) {
    int lin = q * 256 + tid;
    int r = lin >> 4, ch = lin & 15;
    bf16x8 v = *(const bf16x8*)(mixed + (size_t)(t0 + r) * 12288 + (size_t)b * 6144 + n * 384 + 256 + ch * 8);
    int sch = ch ^ ((r >> 3) & 7);
    *(bf16x8*)((char*)tile + r * 256 + sch * 16) = v;
  }
  __syncthreads();
  #pragma unroll
  for (int q = 0; q < 8; ++q) {
    int lin = q * 256 + tid;
    int d = lin >> 4, tc = (lin & 15) * 8;
    bf16x8 v;
    #pragma unroll
    for (int j = 0; j < 8; ++j) {
      int row = tc + j;
      int swb = (d * 2) ^ (((row >> 3) & 7) << 4);
      v[j] = *(const __bf16*)((const char*)tile + row * 256 + swb);
    }
    *(bf16x8*)(vbuf + ((size_t)bn * 128 + d) * 2048 + t0 + tc) = v;
  }
}

// ---------------- flash attention (R7/R9 verified version) ----------------
// grid (8 pairs, 32 bn); 512 threads = 8 waves x 16 q-rows. Mirror-pair qt
// loop: exactly 34 KV iters/block; LDS 84KB pins 1 block/CU.
// Fixed-reference softmax P = exp(S*sc - 8); l reduced once per q-tile.
struct SmemA {
  __bf16 k[2][64][128];   // 32KB  (aliased by Q staging area)
  __bf16 v[2][128][64];   // 32KB
  __bf16 p[8][16][64];    // 16KB per-wave private P
};
union SmemUA { __bf16 q[128][128]; SmemA s; char pad[86016]; };

__global__ __launch_bounds__(512, 1)
void attn_kernel(const __bf16* __restrict__ mixed, const __bf16* __restrict__ vbuf,
                 __bf16* __restrict__ ctx) {
  const int tid = threadIdx.x, lane = tid & 63, w = tid >> 6;   // w in 0..7
  const int bn = blockIdx.y;
  const int b = bn >> 4, n = bn & 15;
  const int fr = lane & 15, g = lane >> 4;

  __shared__ SmemUA sm;
  const __bf16* vb = vbuf + (size_t)bn * 128 * 2048;
  const __bf16* mixb = mixed + (size_t)b * 6144 + n * 384;
  char* pbase = (char*)sm.s.p + w * 2048;

  auto stage_kv = [&](int k0, int buf) {
    #pragma unroll
    for (int qq = 0; qq < 2; ++qq) {
      int t = qq * 512 + tid;
      int r = t >> 4, ch = (t & 15) ^ (r & 7);
      g2l16(mixb + (size_t)(k0 + r) * 12288 + 128 + ch * 8,
            (char*)sm.s.k[buf] + qq * 8192 + w * 1024);
    }
    #pragma unroll
    for (int qq = 0; qq < 2; ++qq) {
      int t = qq * 512 + tid;
      int d = t >> 3, i = (t & 7) ^ (d & 7);
      g2l16(vb + (size_t)d * 2048 + k0 + i * 8,
            (char*)sm.s.v[buf] + qq * 8192 + w * 1024);
    }
  };

  #pragma unroll 1
  for (int phase = 0; phase < 2; ++phase) {
    const int qt = phase ? (int)blockIdx.x : (15 - (int)blockIdx.x);  // heavy first
    const int qs = qt * 128;

    __syncthreads();   // prior phase fully done before Q restage (aliases K dbuf)

    // ---- stage Q [128][128] (pre-swizzled source) ----
    #pragma unroll
    for (int qq = 0; qq < 4; ++qq) {
      int t = qq * 512 + tid;
      int r = t >> 4, ch = (t & 15) ^ (r & 7);
      g2l16(mixb + (size_t)(qs + r) * 12288 + ch * 8,
            (char*)sm.q + qq * 8192 + w * 1024);
    }
    asm volatile("s_waitcnt vmcnt(0)" ::: "memory");
    __syncthreads();

    bf16x8 qf[4];
    {
      const int row = w * 16 + fr;
      #pragma unroll
      for (int ks = 0; ks < 4; ++ks) {
        int ch = (ks * 4 + g) ^ (row & 7);
        qf[ks] = *(const bf16x8*)((const char*)sm.q + row * 256 + ch * 16);
      }
    }
    asm volatile("s_waitcnt lgkmcnt(0)" ::: "memory");
    __syncthreads();   // all qf reads landed before K staging overwrites Q area

    f32x4 O[8] = {};
    float lsum[4] = {0.f, 0.f, 0.f, 0.f};

    const int nt = (qs + 128) >> 6;
    int cur = 0;
    stage_kv(0, 0);

    #pragma unroll 1
    for (int it = 0; it < nt; ++it) {
      const int k0 = it * 64;
      asm volatile("s_waitcnt vmcnt(0)" ::: "memory");   // buf[cur] landed
      __syncthreads();                                    // ...for ALL waves
      if (it + 1 < nt) stage_kv((it + 1) * 64, cur ^ 1);  // fly under compute

      // ---- QK^T: S[16 q][64 kv] per wave ----
      f32x4 S[4] = {};
      __builtin_amdgcn_s_setprio(1);
      #pragma unroll
      for (int ks = 0; ks < 4; ++ks) {
        bf16x8 kf[4];
        #pragma unroll
        for (int fn = 0; fn < 4; ++fn) {
          int row = fn * 16 + fr;
          int ch = (ks * 4 + g) ^ (row & 7);
          kf[fn] = *(const bf16x8*)((const char*)sm.s.k[cur] + row * 256 + ch * 16);
        }
        #pragma unroll
        for (int fn = 0; fn < 4; ++fn)
          S[fn] = __builtin_amdgcn_mfma_f32_16x16x32_bf16(qf[ks], kf[fn], S[fn], 0, 0, 0);
      }
      __builtin_amdgcn_s_setprio(0);

      // ---- fixed-reference softmax: P = exp(S*sc - 8), masked -> 0 ----
      const float sc = 0.08838834764831845f;   // 1/sqrt(128)
      const bool needmask = (k0 + 63 > qs + w * 16);
      #pragma unroll
      for (int fn = 0; fn < 4; ++fn)
        #pragma unroll
        for (int r = 0; r < 4; ++r) {
          float p = __expf(fmaf(S[fn][r], sc, -8.0f));
          if (needmask) {
            int qrow = qs + w * 16 + g * 4 + r;
            int kcol = k0 + fn * 16 + fr;
            if (kcol > qrow) p = 0.f;
          }
          S[fn][r] = p;
          lsum[r] += p;
        }

      // ---- P -> LDS (per-wave private, swizzled) ----
      #pragma unroll
      for (int fn = 0; fn < 4; ++fn)
        #pragma unroll
        for (int r = 0; r < 4; ++r) {
          int prow = g * 4 + r;
          int colb = (fn * 16 + fr) * 2;
          *(__bf16*)(pbase + prow * 128 + (colb ^ ((prow & 7) << 4))) = (__bf16)S[fn][r];
        }

      // ---- PV: O += P * V (no rescale -- P reference is fixed) ----
      __builtin_amdgcn_s_setprio(1);
      #pragma unroll
      for (int ks2 = 0; ks2 < 2; ++ks2) {
        bf16x8 pa;
        {
          int ch = (ks2 * 4 + g) ^ (fr & 7);
          pa = *(const bf16x8*)(pbase + fr * 128 + ch * 16);
        }
        #pragma unroll
        for (int fn2 = 0; fn2 < 8; ++fn2) {
          int vrow = fn2 * 16 + fr;
          int ch = (ks2 * 4 + g) ^ (vrow & 7);
          bf16x8 vf = *(const bf16x8*)((const char*)sm.s.v[cur] + vrow * 128 + ch * 16);
          O[fn2] = __builtin_amdgcn_mfma_f32_16x16x32_bf16(pa, vf, O[fn2], 0, 0, 0);
        }
      }
      __builtin_amdgcn_s_setprio(0);
      cur ^= 1;
    }

    // ---- epilogue: one cross-lane l reduce per q-tile, then ctx write ----
    #pragma unroll
    for (int r = 0; r < 4; ++r) {
      float l = lsum[r];
      #pragma unroll
      for (int off = 1; off < 16; off <<= 1)
        l += __shfl_xor(l, off);
      float inv = 1.f / l;
      int qrow = qs + w * 16 + g * 4 + r;
      size_t rowb = ((size_t)qrow * 2 + b) * 2048 + n * 128;
      #pragma unroll
      for (int fn2 = 0; fn2 < 8; ++fn2)
        ctx[rowb + fn2 * 16 + fr] = (__bf16)(O[fn2][r] * inv);
    }
  }
}

extern "C" void kernel_launch(void* const* d_in, const int* in_sizes, int n_in,
                              void* d_out, int out_size, void* d_ws, size_t ws_size,
                              hipStream_t stream) {
  const float* x    = (const float*)d_in[0];
  // d_in[1] = mask: structurally causal, applied analytically in attn_kernel
  const float* wqkv = (const float*)d_in[2];
  const float* bqkv = (const float*)d_in[3];
  const float* wd   = (const float*)d_in[4];
  const float* bd   = (const float*)d_in[5];

  char* ws = (char*)d_ws;
  __bf16* xb    = (__bf16*)(ws);                 // 16.8MB (reused as ctx later)
  __bf16* wqkvb = (__bf16*)(ws + 16777216);      // 25.2MB
  __bf16* wdb   = (__bf16*)(ws + 41943040);      // 8.4MB
  __bf16* mixed = (__bf16*)(ws + 50331648);      // 50.3MB
  __bf16* vbuf  = (__bf16*)(ws + 100663296);     // 16.8MB  (total 117.4MB)
  __bf16* ctx   = xb;                            // xb dead after QKV GEMM

  cvt3_kernel<<<dim3(24576), 256, 0, stream>>>(x, wqkv, wd, xb, wqkvb, wdb);

  // QKV: BM=128 x BN=384 -> grid 16x32 = 512 blocks = 2 exact rounds @1/CU
  gemm32<3,1><<<dim3(16, 32), 512, 0, stream>>>(xb, wqkvb, bqkv, (void*)mixed, MROWS, NQKV, 2048);
  vtrans<<<dim3(32, 16), 256, 0, stream>>>(mixed, vbuf);
  attn_kernel<<<dim3(8, 32), 512, 0, stream>>>(mixed, vbuf, ctx);
  // dense: BM=128 x BN=256 -> grid 8x32 = 256 blocks = 1 exact round
  gemm32<2,0><<<dim3(8, 32), 512, 0, stream>>>(ctx, wdb, bd, d_out, MROWS, 2048, 2048);
}

// Round 12
// 220.146 us; speedup vs baseline: 1.0870x; 1.0646x over previous
//
#include <hip/hip_runtime.h>
#include <hip/hip_bf16.h>

// Fused attention block: QKV proj -> causal MHA -> dense proj.
// SEQ=2048, BATCH=2, HIDDEN=2048, HEADS=16, HEAD_DIM=128.
// R12: GEMMs reverted to R9's verified gemm4p (16x16x32, 4-phase; the 32x32
// experiment R10/R11 was net-negative at equal MfmaUtil). attn = R7/R9
// kernel + XCD-locality block remap: all 8 q-pair blocks of one head land on
// one XCD (id = (bn&7) + 8*pair + 64*(bn>>3)) so the ~1MB K/V panel is
// fetched by one L2 instead of eight. Bijective remap: placement assumption
// wrong => perf-neutral, never incorrect; per-block work unchanged (34 iters).

typedef __bf16 bf16x8 __attribute__((ext_vector_type(8)));
typedef __bf16 bf16x4 __attribute__((ext_vector_type(4)));
typedef float  f32x4  __attribute__((ext_vector_type(4)));

#define MROWS 4096   // SEQ*BATCH
#define NQKV  6144   // 3*HIDDEN

__device__ __forceinline__ void g2l16(const void* g, void* l) {
  __builtin_amdgcn_global_load_lds(
      (const __attribute__((address_space(1))) unsigned int*)g,
      (__attribute__((address_space(3))) unsigned int*)l, 16, 0, 0);
}

// ---------------- fp32 -> bf16 convert (all three tensors, one launch) ------
__global__ void cvt3_kernel(const float* __restrict__ x, const float* __restrict__ wq,
                            const float* __restrict__ wd, __bf16* __restrict__ xb,
                            __bf16* __restrict__ wqb, __bf16* __restrict__ wdb) {
  const int N1 = 2097152, N2 = 3145728;   // float4 counts: x, wqkv (wd = rest)
  int i = blockIdx.x * 256 + threadIdx.x;
  const float4* src; bf16x4* dst; int j;
  if (i < N1)           { src = (const float4*)x;  dst = (bf16x4*)xb;  j = i; }
  else if (i < N1 + N2) { src = (const float4*)wq; dst = (bf16x4*)wqb; j = i - N1; }
  else                  { src = (const float4*)wd; dst = (bf16x4*)wdb; j = i - N1 - N2; }
  float4 v = src[j];
  bf16x4 o = { (__bf16)v.x, (__bf16)v.y, (__bf16)v.z, (__bf16)v.w };
  dst[j] = o;
}

// ---------------- 4-phase GEMM: C[M][N] = A[M][K] * B[N][K]^T + bias --------
// (R5 schedule; NF generalized 3..6. See R5 notes for hazard derivation.)
#define MM_CL(MH, NFI)                                                          \
  { _Pragma("unroll")                                                           \
    for (int mf = 0; mf < MF/2; ++mf) {                                         \
      f32x4& a0 = acc[(MH)*(MF/2)+mf][NFI];                                     \
      a0 = __builtin_amdgcn_mfma_f32_16x16x32_bf16(afr[mf][0], bfr[NFI][0], a0, 0,0,0); \
      a0 = __builtin_amdgcn_mfma_f32_16x16x32_bf16(afr[mf][1], bfr[NFI][1], a0, 0,0,0); \
    } }
#define LDB(NFI)                                                                \
  { int row = wn*(BN/4) + (NFI)*16 + fr;                                        \
    _Pragma("unroll")                                                           \
    for (int ks = 0; ks < 2; ++ks)                                              \
      bfr[NFI][ks] = *(const bf16x8*)(buf + ABYTES + row*128 + (((ks*4+g)^(row&7))<<4)); }
#define SBAR asm volatile("s_barrier" ::: "memory")
#define LGKM0 asm volatile("s_waitcnt lgkmcnt(0)" ::: "memory")

template<int MF, int NF, int C_BF16>
__global__ __launch_bounds__(512, 1)
void gemm4p(const __bf16* __restrict__ A, const __bf16* __restrict__ B,
            const float* __restrict__ bias, void* __restrict__ Cout,
            int M, int N, int K) {
  constexpr int BM = 32*MF, BN = 64*NF;
  constexpr int ABYTES = BM*128;
  constexpr int LA = BM/128;        // g2l16/thread per A-region
  constexpr int LG1 = NF-2;         // g2l16/thread for B-G1
  constexpr int VMC = LA + 2;       // boundary vmcnt

  const int tid = threadIdx.x, lane = tid & 63, w = tid >> 6;
  const int wm = w >> 2, wn = w & 3;
  const int m0 = blockIdx.y*BM, n0 = blockIdx.x*BN;
  const int fr = lane & 15, g = lane >> 4;
  const int l8 = lane >> 3;
  const int swch = (lane & 7) ^ l8;

  __shared__ char smem[2][ABYTES + BN*128];

  f32x4 acc[MF][NF] = {};
  bf16x8 afr[MF/2][2], bfr[NF][2];

  const int nt = K >> 6;

  auto stA = [&](int kt2, int mh, char* dst) {
    #pragma unroll
    for (int q = 0; q < LA; ++q) {
      int uu = q*8 + w;
      int s = uu / ((BM/4)/8);
      int rb = (2*s + mh)*(BM/4) + (uu % ((BM/4)/8))*8;
      g2l16(A + (size_t)(m0 + rb + l8)*K + kt2*64 + swch*8, dst + rb*128);
    }
  };
  auto stB0 = [&](int kt2, char* dst) {          // G0: 4 strips, rows 0..31
    #pragma unroll
    for (int q = 0; q < 2; ++q) {
      int idx0 = q*64 + w*8;
      int drow = (idx0 >> 5)*(BN/4) + (idx0 & 31);
      g2l16(B + (size_t)(n0 + drow + l8)*K + kt2*64 + swch*8, dst + ABYTES + drow*128);
    }
  };
  auto stB1 = [&](int kt2, char* dst) {          // G1: 4 strips, rows 32..
    #pragma unroll
    for (int q = 0; q < LG1; ++q) {
      int idx0 = q*64 + w*8;
      int drow = (idx0 / ((NF-2)*16))*(BN/4) + 32 + idx0 % ((NF-2)*16);
      g2l16(B + (size_t)(n0 + drow + l8)*K + kt2*64 + swch*8, dst + ABYTES + drow*128);
    }
  };
  auto ldA = [&](const char* buf, int mh) {
    const char* ah = buf + wm*(BM/2)*128;
    #pragma unroll
    for (int mf = 0; mf < MF/2; ++mf) {
      int row = (mh*(MF/2)+mf)*16 + fr;
      #pragma unroll
      for (int ks = 0; ks < 2; ++ks)
        afr[mf][ks] = *(const bf16x8*)(ah + row*128 + (((ks*4+g)^(row&7))<<4));
    }
  };

  auto tile = [&](int kt, char* buf, char* nbuf) {
    // ph0: read A-mh0 + B-G0; stage A1(kt+1)->nbuf
    ldA(buf, 0); LDB(0); LDB(1);
    stA(kt+1, 1, nbuf);
    SBAR; LGKM0;
    __builtin_amdgcn_s_setprio(1); MM_CL(0,0); MM_CL(0,1); __builtin_amdgcn_s_setprio(0);
    SBAR;
    // ph1: read B-G1; stage B-G1(kt+1)->nbuf
    LDB(2);
    if constexpr (NF >= 4) { LDB(3); }
    if constexpr (NF >= 5) { LDB(4); }
    if constexpr (NF >= 6) { LDB(5); }
    stB1(kt+1, nbuf);
    SBAR; LGKM0;
    __builtin_amdgcn_s_setprio(1);
    MM_CL(0,2);
    if constexpr (NF >= 4) { MM_CL(0,3); }
    if constexpr (NF >= 5) { MM_CL(0,4); }
    if constexpr (NF >= 6) { MM_CL(0,5); }
    __builtin_amdgcn_s_setprio(0);
    SBAR;
    // ph2: read A-mh1; stage A0(kt+2)->buf (A0 reads done at ph0)
    ldA(buf, 1);
    stA(kt+2, 0, buf);
    SBAR; LGKM0;
    __builtin_amdgcn_s_setprio(1);
    MM_CL(1,2);
    if constexpr (NF >= 4) { MM_CL(1,3); }
    if constexpr (NF >= 5) { MM_CL(1,4); }
    if constexpr (NF >= 6) { MM_CL(1,5); }
    __builtin_amdgcn_s_setprio(0);
    SBAR;
    // ph3: no reads (B-G0 held); stage B-G0(kt+2)->buf; counted drain.
    stB0(kt+2, buf);
    SBAR;
    __builtin_amdgcn_s_setprio(1); MM_CL(1,0); MM_CL(1,1); __builtin_amdgcn_s_setprio(0);
    asm volatile("s_waitcnt vmcnt(%0)" :: "i"(VMC) : "memory");
    SBAR;
  };

  // prologue: tile0 complete + A0,BG0 of tile1
  stA(0, 0, smem[0]); stB0(0, smem[0]); stB1(0, smem[0]); stA(0, 1, smem[0]);
  stA(1, 0, smem[1]); stB0(1, smem[1]);
  asm volatile("s_waitcnt vmcnt(%0)" :: "i"(VMC) : "memory");
  SBAR;

  for (int kt = 0; kt < nt; kt += 2) {
    tile(kt,     smem[0], smem[1]);
    tile(kt + 1, smem[1], smem[0]);
  }
  // phantom stages read <=384B past panel ends into adjacent mapped ws
  // buffers; their LDS regions are never read again.

  // epilogue: C/D layout col=lane&15, row=(lane>>4)*4+reg (m89/m91-verified)
  const int orow0 = m0 + wm*(BM/2) + g*4;
  const int ocol0 = n0 + wn*(BN/4) + fr;
  #pragma unroll
  for (int nf = 0; nf < NF; ++nf) {
    int col = ocol0 + nf*16;
    float bv = bias[col];
    #pragma unroll
    for (int mf = 0; mf < MF; ++mf) {
      #pragma unroll
      for (int r = 0; r < 4; ++r) {
        float v = acc[mf][nf][r] + bv;
        size_t idx = (size_t)(orow0 + mf*16 + r) * N + col;
        if (C_BF16) ((__bf16*)Cout)[idx] = (__bf16)v;
        else        ((float*)Cout)[idx]  = v;
      }
    }
  }
}

// ---------------- V transpose: mixed V-slice -> vbuf[bn][d][t] ----------------
__global__ __launch_bounds__(256, 2)
void vtrans(const __bf16* __restrict__ mixed, __bf16* __restrict__ vbuf) {
  const int tid = threadIdx.x;
  const int bn = blockIdx.x;          // b*16 + n
  const int b = bn >> 4, n = bn & 15;
  const int t0 = blockIdx.y * 128;
  __shared__ __bf16 tile[128][128];   // swizzled: chunk ^= (row>>3)&7

  #pragma unroll
  for (int q = 0; q < 8; ++q) {
    int lin = q * 256 + tid;
    int r = lin >> 4, ch = lin & 15;
    bf16x8 v = *(const bf16x8*)(mixed + (size_t)(t0 + r) * 12288 + (size_t)b * 6144 + n * 384 + 256 + ch * 8);
    int sch = ch ^ ((r >> 3) & 7);
    *(bf16x8*)((char*)tile + r * 256 + sch * 16) = v;
  }
  __syncthreads();
  #pragma unroll
  for (int q = 0; q < 8; ++q) {
    int lin = q * 256 + tid;
    int d = lin >> 4, tc = (lin & 15) * 8;
    bf16x8 v;
    #pragma unroll
    for (int j = 0; j < 8; ++j) {
      int row = tc + j;
      int swb = (d * 2) ^ (((row >> 3) & 7) << 4);
      v[j] = *(const __bf16*)((const char*)tile + row * 256 + swb);
    }
    *(bf16x8*)(vbuf + ((size_t)bn * 128 + d) * 2048 + t0 + tc) = v;
  }
}

// ---------------- flash attention (R7/R9 verified + XCD-local remap) --------
// flat grid 256; id = (bn&7) + 8*pair + 64*(bn>>3): the 8 q-pair blocks of a
// head share one XCD's L2 (round-robin id%8 dispatch heuristic) -> K/V panel
// fetched once per XCD instead of 8x. 512 threads = 8 waves x 16 q-rows.
// Mirror-pair qt loop: exactly 34 KV iters/block; LDS 84KB pins 1 block/CU.
// Fixed-reference softmax P = exp(S*sc - 8); l reduced once per q-tile.
struct SmemA {
  __bf16 k[2][64][128];   // 32KB  (aliased by Q staging area)
  __bf16 v[2][128][64];   // 32KB
  __bf16 p[8][16][64];    // 16KB per-wave private P
};
union SmemUA { __bf16 q[128][128]; SmemA s; char pad[86016]; };

__global__ __launch_bounds__(512, 1)
void attn_kernel(const __bf16* __restrict__ mixed, const __bf16* __restrict__ vbuf,
                 __bf16* __restrict__ ctx) {
  const int tid = threadIdx.x, lane = tid & 63, w = tid >> 6;   // w in 0..7
  const int id = blockIdx.x;
  const int pr = (id >> 3) & 7;                 // q-pair index 0..7
  const int bn = (id & 7) | ((id >> 6) << 3);   // head id 0..31 (XCD-local)
  const int b = bn >> 4, n = bn & 15;
  const int fr = lane & 15, g = lane >> 4;

  __shared__ SmemUA sm;
  const __bf16* vb = vbuf + (size_t)bn * 128 * 2048;
  const __bf16* mixb = mixed + (size_t)b * 6144 + n * 384;
  char* pbase = (char*)sm.s.p + w * 2048;

  auto stage_kv = [&](int k0, int buf) {
    #pragma unroll
    for (int qq = 0; qq < 2; ++qq) {
      int t = qq * 512 + tid;
      int r = t >> 4, ch = (t & 15) ^ (r & 7);
      g2l16(mixb + (size_t)(k0 + r) * 12288 + 128 + ch * 8,
            (char*)sm.s.k[buf] + qq * 8192 + w * 1024);
    }
    #pragma unroll
    for (int qq = 0; qq < 2; ++qq) {
      int t = qq * 512 + tid;
      int d = t >> 3, i = (t & 7) ^ (d & 7);
      g2l16(vb + (size_t)d * 2048 + k0 + i * 8,
            (char*)sm.s.v[buf] + qq * 8192 + w * 1024);
    }
  };

  #pragma unroll 1
  for (int phase = 0; phase < 2; ++phase) {
    const int qt = phase ? pr : (15 - pr);      // heavy first
    const int qs = qt * 128;

    __syncthreads();   // prior phase fully done before Q restage (aliases K dbuf)

    // ---- stage Q [128][128] (pre-swizzled source) ----
    #pragma unroll
    for (int qq = 0; qq < 4; ++qq) {
      int t = qq * 512 + tid;
      int r = t >> 4, ch = (t & 15) ^ (r & 7);
      g2l16(mixb + (size_t)(qs + r) * 12288 + ch * 8,
            (char*)sm.q + qq * 8192 + w * 1024);
    }
    asm volatile("s_waitcnt vmcnt(0)" ::: "memory");
    __syncthreads();

    bf16x8 qf[4];
    {
      const int row = w * 16 + fr;
      #pragma unroll
      for (int ks = 0; ks < 4; ++ks) {
        int ch = (ks * 4 + g) ^ (row & 7);
        qf[ks] = *(const bf16x8*)((const char*)sm.q + row * 256 + ch * 16);
      }
    }
    asm volatile("s_waitcnt lgkmcnt(0)" ::: "memory");
    __syncthreads();   // all qf reads landed before K staging overwrites Q area

    f32x4 O[8] = {};
    float lsum[4] = {0.f, 0.f, 0.f, 0.f};

    const int nt = (qs + 128) >> 6;
    int cur = 0;
    stage_kv(0, 0);

    #pragma unroll 1
    for (int it = 0; it < nt; ++it) {
      const int k0 = it * 64;
      asm volatile("s_waitcnt vmcnt(0)" ::: "memory");   // buf[cur] landed
      __syncthreads();                                    // ...for ALL waves
      if (it + 1 < nt) stage_kv((it + 1) * 64, cur ^ 1);  // fly under compute

      // ---- QK^T: S[16 q][64 kv] per wave ----
      f32x4 S[4] = {};
      __builtin_amdgcn_s_setprio(1);
      #pragma unroll
      for (int ks = 0; ks < 4; ++ks) {
        bf16x8 kf[4];
        #pragma unroll
        for (int fn = 0; fn < 4; ++fn) {
          int row = fn * 16 + fr;
          int ch = (ks * 4 + g) ^ (row & 7);
          kf[fn] = *(const bf16x8*)((const char*)sm.s.k[cur] + row * 256 + ch * 16);
        }
        #pragma unroll
        for (int fn = 0; fn < 4; ++fn)
          S[fn] = __builtin_amdgcn_mfma_f32_16x16x32_bf16(qf[ks], kf[fn], S[fn], 0, 0, 0);
      }
      __builtin_amdgcn_s_setprio(0);

      // ---- fixed-reference softmax: P = exp(S*sc - 8), masked -> 0 ----
      const float sc = 0.08838834764831845f;   // 1/sqrt(128)
      const bool needmask = (k0 + 63 > qs + w * 16);
      #pragma unroll
      for (int fn = 0; fn < 4; ++fn)
        #pragma unroll
        for (int r = 0; r < 4; ++r) {
          float p = __expf(fmaf(S[fn][r], sc, -8.0f));
          if (needmask) {
            int qrow = qs + w * 16 + g * 4 + r;
            int kcol = k0 + fn * 16 + fr;
            if (kcol > qrow) p = 0.f;
          }
          S[fn][r] = p;
          lsum[r] += p;
        }

      // ---- P -> LDS (per-wave private, swizzled) ----
      #pragma unroll
      for (int fn = 0; fn < 4; ++fn)
        #pragma unroll
        for (int r = 0; r < 4; ++r) {
          int prow = g * 4 + r;
          int colb = (fn * 16 + fr) * 2;
          *(__bf16*)(pbase + prow * 128 + (colb ^ ((prow & 7) << 4))) = (__bf16)S[fn][r];
        }

      // ---- PV: O += P * V (no rescale -- P reference is fixed) ----
      __builtin_amdgcn_s_setprio(1);
      #pragma unroll
      for (int ks2 = 0; ks2 < 2; ++ks2) {
        bf16x8 pa;
        {
          int ch = (ks2 * 4 + g) ^ (fr & 7);
          pa = *(const bf16x8*)(pbase + fr * 128 + ch * 16);
        }
        #pragma unroll
        for (int fn2 = 0; fn2 < 8; ++fn2) {
          int vrow = fn2 * 16 + fr;
          int ch = (ks2 * 4 + g) ^ (vrow & 7);
          bf16x8 vf = *(const bf16x8*)((const char*)sm.s.v[cur] + vrow * 128 + ch * 16);
          O[fn2] = __builtin_amdgcn_mfma_f32_16x16x32_bf16(pa, vf, O[fn2], 0, 0, 0);
        }
      }
      __builtin_amdgcn_s_setprio(0);
      cur ^= 1;
    }

    // ---- epilogue: one cross-lane l reduce per q-tile, then ctx write ----
    #pragma unroll
    for (int r = 0; r < 4; ++r) {
      float l = lsum[r];
      #pragma unroll
      for (int off = 1; off < 16; off <<= 1)
        l += __shfl_xor(l, off);
      float inv = 1.f / l;
      int qrow = qs + w * 16 + g * 4 + r;
      size_t rowb = ((size_t)qrow * 2 + b) * 2048 + n * 128;
      #pragma unroll
      for (int fn2 = 0; fn2 < 8; ++fn2)
        ctx[rowb + fn2 * 16 + fr] = (__bf16)(O[fn2][r] * inv);
    }
  }
}

extern "C" void kernel_launch(void* const* d_in, const int* in_sizes, int n_in,
                              void* d_out, int out_size, void* d_ws, size_t ws_size,
                              hipStream_t stream) {
  const float* x    = (const float*)d_in[0];
  // d_in[1] = mask: structurally causal, applied analytically in attn_kernel
  const float* wqkv = (const float*)d_in[2];
  const float* bqkv = (const float*)d_in[3];
  const float* wd   = (const float*)d_in[4];
  const float* bd   = (const float*)d_in[5];

  char* ws = (char*)d_ws;
  __bf16* xb    = (__bf16*)(ws);                 // 16.8MB (reused as ctx later)
  __bf16* wqkvb = (__bf16*)(ws + 16777216);      // 25.2MB
  __bf16* wdb   = (__bf16*)(ws + 41943040);      // 8.4MB
  __bf16* mixed = (__bf16*)(ws + 50331648);      // 50.3MB
  __bf16* vbuf  = (__bf16*)(ws + 100663296);     // 16.8MB  (total 117.4MB)
  __bf16* ctx   = xb;                            // xb dead after QKV GEMM

  cvt3_kernel<<<dim3(24576), 256, 0, stream>>>(x, wqkv, wd, xb, wqkvb, wdb);

  // QKV: BM=128 x BN=384 -> grid 16x32 = 512 blocks = 2 exact rounds @1/CU
  gemm4p<4,6,1><<<dim3(16, 32), 512, 0, stream>>>(xb, wqkvb, bqkv, (void*)mixed, MROWS, NQKV, 2048);
  vtrans<<<dim3(32, 16), 256, 0, stream>>>(mixed, vbuf);
  attn_kernel<<<dim3(256), 512, 0, stream>>>(mixed, vbuf, ctx);
  // dense: BM=128 x BN=256 -> grid 8x32 = 256 blocks = 1 exact round
  gemm4p<4,4,0><<<dim3(8, 32), 512, 0, stream>>>(ctx, wdb, bd, d_out, MROWS, 2048, 2048);
}